// Round 1
// baseline (552.660 us; speedup 1.0000x reference)
//
#include <hip/hip_runtime.h>
#include <hip/hip_bf16.h>
#include <stdint.h>

#define D_MODEL 1024
#define NHEADS 16
#define HDIM 64
#define BATCH 4
#define SEQ 2048
#define M_ROWS (BATCH*SEQ)                     // 8192
#define BHTD ((size_t)BATCH*NHEADS*SEQ*HDIM)   // 8388608 elems

typedef __attribute__((ext_vector_type(8))) short bf16x8;
typedef __attribute__((ext_vector_type(4))) float f32x4;
typedef __attribute__((address_space(1))) uint32_t as1_u32;
typedef __attribute__((address_space(3))) uint32_t as3_u32;

__device__ __forceinline__ void gload_lds16(const void* g, void* l) {
    __builtin_amdgcn_global_load_lds((const as1_u32*)(uintptr_t)g,
                                     (as3_u32*)(uintptr_t)l, 16, 0, 0);
}

__device__ __forceinline__ short f2bf(float f) {
    __hip_bfloat16 h = __float2bfloat16(f);
    return *reinterpret_cast<short*>(&h);
}

// ---------------------------------------------------------------- conversions
__global__ void f32_to_bf16_k(const float* __restrict__ in, short* __restrict__ out, int n) {
    int i = (blockIdx.x * blockDim.x + threadIdx.x) * 4;
    if (i >= n) return;
    float4 v = *(const float4*)&in[i];
    short4 r;
    r.x = f2bf(v.x); r.y = f2bf(v.y); r.z = f2bf(v.z); r.w = f2bf(v.w);
    *(short4*)&out[i] = r;
}

// transpose 1024x1024 fp32 [k][n] -> bf16 [n][k]; z selects {wq,wk,wv,wo}
__global__ void transpose_pack_k(const float* __restrict__ wq, const float* __restrict__ wk,
                                 const float* __restrict__ wv, const float* __restrict__ wo,
                                 short* __restrict__ qkvT, short* __restrict__ woT) {
    __shared__ float tile[32][33];
    int z = blockIdx.z;
    const float* src = (z == 0) ? wq : (z == 1) ? wk : (z == 2) ? wv : wo;
    short* dst = (z < 3) ? (qkvT + (size_t)z * D_MODEL * D_MODEL) : woT;
    int bx = blockIdx.x, by = blockIdx.y;
    int tx = threadIdx.x, ty = threadIdx.y;
#pragma unroll
    for (int r = 0; r < 32; r += 8)
        tile[ty + r][tx] = src[(size_t)(by * 32 + ty + r) * D_MODEL + bx * 32 + tx];
    __syncthreads();
#pragma unroll
    for (int r = 0; r < 32; r += 8)
        dst[(size_t)(bx * 32 + ty + r) * D_MODEL + by * 32 + tx] = f2bf(tile[tx][ty + r]);
}

// ---------------------------------------------------------------- GEMM 128x128x32
// A [M][K] bf16 row-major, Bt [N][K] bf16 (B transposed). 256 thr, 4 waves, each 64x64.
// MODE 0: QKV scatter -> outb [3][B,H,T,D] bf16, bias b0/b1/b2, Q scaled by 0.125
// MODE 1: outf [M][N] fp32 + bias b0
template <int MODE>
__global__ __launch_bounds__(256) void gemm128(const short* __restrict__ A,
                                               const short* __restrict__ Bt,
                                               const float* __restrict__ b0,
                                               const float* __restrict__ b1,
                                               const float* __restrict__ b2,
                                               short* __restrict__ outb,
                                               float* __restrict__ outf,
                                               int K) {
    __shared__ short As[128 * 32];
    __shared__ short Bs[128 * 32];
    int tid = threadIdx.x;
    int lane = tid & 63, wid = tid >> 6;
    int wr = wid >> 1, wc = wid & 1;
    int lr = lane & 15, lg = lane >> 4;
    int mb = blockIdx.x * 128;
    int nb = blockIdx.y * 128;

    f32x4 acc[4][4] = {};
    int nk = K / 32;
    int r = tid >> 2, seg = tid & 3;
    for (int kt = 0; kt < nk; ++kt) {
        int kb = kt * 32;
        __syncthreads();
        const short* ga = A + (size_t)(mb + r) * K + kb + seg * 8;
        const short* gb = Bt + (size_t)(nb + r) * K + kb + seg * 8;
        gload_lds16(ga, &As[tid * 8]);
        gload_lds16(ga + (size_t)64 * K, &As[2048 + tid * 8]);
        gload_lds16(gb, &Bs[tid * 8]);
        gload_lds16(gb + (size_t)64 * K, &Bs[2048 + tid * 8]);
        __syncthreads();
        bf16x8 af[4], bfr[4];
#pragma unroll
        for (int ms = 0; ms < 4; ++ms)
            af[ms] = *(const bf16x8*)&As[(wr * 64 + ms * 16 + lr) * 32 + lg * 8];
#pragma unroll
        for (int ns = 0; ns < 4; ++ns)
            bfr[ns] = *(const bf16x8*)&Bs[(wc * 64 + ns * 16 + lr) * 32 + lg * 8];
#pragma unroll
        for (int ms = 0; ms < 4; ++ms)
#pragma unroll
            for (int ns = 0; ns < 4; ++ns)
                acc[ms][ns] = __builtin_amdgcn_mfma_f32_16x16x32_bf16(af[ms], bfr[ns], acc[ms][ns], 0, 0, 0);
    }
    // epilogue: C row = mb+wr*64+ms*16+lg*4+j, col = nb+wc*64+ns*16+lr
#pragma unroll
    for (int ms = 0; ms < 4; ++ms) {
        int row0 = mb + wr * 64 + ms * 16 + lg * 4;
#pragma unroll
        for (int ns = 0; ns < 4; ++ns) {
            int col = nb + wc * 64 + ns * 16 + lr;
            if (MODE == 0) {
                int sec = col >> 10;
                int nn = col & 1023;
                float bias = (sec == 0) ? b0[nn] : (sec == 1) ? b1[nn] : b2[nn];
                int h = nn >> 6, d = nn & 63;
#pragma unroll
                for (int j = 0; j < 4; ++j) {
                    int m = row0 + j;
                    int bb = m >> 11, t = m & 2047;
                    float v = acc[ms][ns][j] + bias;
                    if (sec == 0) v *= 0.125f;  // 1/sqrt(64) folded into Q
                    outb[(size_t)sec * BHTD + (((size_t)(bb * NHEADS + h)) * SEQ + t) * HDIM + d] = f2bf(v);
                }
            } else {
                float bias = b0[col];
#pragma unroll
                for (int j = 0; j < 4; ++j)
                    outf[(size_t)(row0 + j) * D_MODEL + col] = acc[ms][ns][j] + bias;
            }
        }
    }
}

// ---------------------------------------------------------------- flash attention
// grid (T/64, B*H); 256 thr = 4 waves; wave w owns q rows qbase+w*16..+15.
// Q pre-scaled by 1/sqrt(Dh). KV blocks of 32, causal.
__global__ __launch_bounds__(256) void attn_kernel(const short* __restrict__ Q,
                                                   const short* __restrict__ Kb,
                                                   const short* __restrict__ Vb,
                                                   short* __restrict__ attn_out) {
    __shared__ short Ks[32 * 64];       // [kv][d]
    __shared__ short Vt[64 * 32];       // [d][kv]
    __shared__ short Ps[4 * 16 * 32];   // per-wave P tile [16][32]
    int tid = threadIdx.x, lane = tid & 63, w = tid >> 6;
    int lr = lane & 15, lg = lane >> 4;
    int qblk = blockIdx.x;
    int bh = blockIdx.y;
    int b = bh >> 4, h = bh & 15;
    int qbase = qblk * 64;
    const short* Qp = Q + (size_t)bh * SEQ * HDIM;
    const short* Kp = Kb + (size_t)bh * SEQ * HDIM;
    const short* Vp = Vb + (size_t)bh * SEQ * HDIM;

    int qrowA = qbase + w * 16 + lr;  // A-frag row for this lane
    bf16x8 qf[2];
    qf[0] = *(const bf16x8*)&Qp[(size_t)qrowA * HDIM + lg * 8];
    qf[1] = *(const bf16x8*)&Qp[(size_t)qrowA * HDIM + 32 + lg * 8];

    f32x4 o[4] = {};
    float mred[4], lred[4];
#pragma unroll
    for (int j = 0; j < 4; ++j) { mred[j] = -3e38f; lred[j] = 0.f; }

    int qg0 = qbase + w * 16 + lg * 4;  // C-layout row base
    int nkb = (qbase + 64) / 32;
    for (int kvb = 0; kvb < nkb; ++kvb) {
        int tb = kvb * 32;
        __syncthreads();
        // stage K [32][64] via async direct-to-LDS
        gload_lds16(Kp + (size_t)(tb + (tid >> 3)) * HDIM + (tid & 7) * 8, &Ks[tid * 8]);
        // stage V transposed [d][kv] via regs
        {
            bf16x8 v = *(const bf16x8*)&Vp[(size_t)(tb + (tid >> 3)) * HDIM + (tid & 7) * 8];
            int vrow = tid >> 3, dbase = (tid & 7) * 8;
#pragma unroll
            for (int j = 0; j < 8; ++j) Vt[(dbase + j) * 32 + vrow] = v[j];
        }
        __syncthreads();
        // S = Q K^T : two 16-col tiles
        f32x4 s[2];
#pragma unroll
        for (int nt = 0; nt < 2; ++nt) {
            f32x4 z = {};
#pragma unroll
            for (int kp = 0; kp < 2; ++kp) {
                bf16x8 kf = *(const bf16x8*)&Ks[(nt * 16 + lr) * 64 + kp * 32 + lg * 8];
                z = __builtin_amdgcn_mfma_f32_16x16x32_bf16(qf[kp], kf, z, 0, 0, 0);
            }
            s[nt] = z;
        }
        // online softmax (rows live in 16-lane groups; reduce over lr)
        float alpha[4], p[2][4];
#pragma unroll
        for (int j = 0; j < 4; ++j) {
            int qg = qg0 + j;
            bool ok0 = (tb + lr) <= qg;
            bool ok1 = (tb + 16 + lr) <= qg;
            float s0 = ok0 ? s[0][j] : -3e38f;
            float s1 = ok1 ? s[1][j] : -3e38f;
            float mv = fmaxf(s0, s1);
            mv = fmaxf(mv, __shfl_xor(mv, 1));
            mv = fmaxf(mv, __shfl_xor(mv, 2));
            mv = fmaxf(mv, __shfl_xor(mv, 4));
            mv = fmaxf(mv, __shfl_xor(mv, 8));
            float mn = fmaxf(mred[j], mv);
            alpha[j] = __expf(mred[j] - mn);
            mred[j] = mn;
            float p0 = ok0 ? __expf(s[0][j] - mn) : 0.f;
            float p1 = ok1 ? __expf(s[1][j] - mn) : 0.f;
            p[0][j] = p0; p[1][j] = p1;
            float ps = p0 + p1;
            ps += __shfl_xor(ps, 1);
            ps += __shfl_xor(ps, 2);
            ps += __shfl_xor(ps, 4);
            ps += __shfl_xor(ps, 8);
            lred[j] = lred[j] * alpha[j] + ps;
        }
#pragma unroll
        for (int dt = 0; dt < 4; ++dt)
#pragma unroll
            for (int j = 0; j < 4; ++j) o[dt][j] *= alpha[j];
        // P (C-layout) -> LDS [16][32] bf16 -> A-frag
#pragma unroll
        for (int nt = 0; nt < 2; ++nt)
#pragma unroll
            for (int j = 0; j < 4; ++j)
                Ps[w * 512 + (lg * 4 + j) * 32 + nt * 16 + lr] = f2bf(p[nt][j]);
        bf16x8 pf = *(const bf16x8*)&Ps[w * 512 + lr * 32 + lg * 8];
#pragma unroll
        for (int dt = 0; dt < 4; ++dt) {
            bf16x8 vf = *(const bf16x8*)&Vt[(dt * 16 + lr) * 32 + lg * 8];
            o[dt] = __builtin_amdgcn_mfma_f32_16x16x32_bf16(pf, vf, o[dt], 0, 0, 0);
        }
    }
    // epilogue -> attn_out [B][T][H*64] bf16
#pragma unroll
    for (int dt = 0; dt < 4; ++dt)
#pragma unroll
        for (int j = 0; j < 4; ++j) {
            int qg = qg0 + j;
            float v = o[dt][j] / lred[j];
            attn_out[((size_t)(b * SEQ) + qg) * D_MODEL + h * HDIM + dt * 16 + lr] = f2bf(v);
        }
}

// ---------------------------------------------------------------- launch
extern "C" void kernel_launch(void* const* d_in, const int* in_sizes, int n_in,
                              void* d_out, int out_size, void* d_ws, size_t ws_size,
                              hipStream_t stream) {
    const float* x  = (const float*)d_in[0];
    const float* wq = (const float*)d_in[1];
    const float* bq = (const float*)d_in[2];
    const float* wk = (const float*)d_in[3];
    const float* bk = (const float*)d_in[4];
    const float* wv = (const float*)d_in[5];
    const float* bv = (const float*)d_in[6];
    const float* wo = (const float*)d_in[7];
    const float* bo = (const float*)d_in[8];
    float* out = (float*)d_out;

    char* ws = (char*)d_ws;
    size_t off = 0;
    auto alloc = [&](size_t bytes) {
        void* p = ws + off;
        off += (bytes + 255) & ~(size_t)255;
        return p;
    };
    short* xb   = (short*)alloc((size_t)M_ROWS * D_MODEL * 2);   // x bf16
    short* qkvT = (short*)alloc((size_t)3 * D_MODEL * D_MODEL * 2);
    short* woT  = (short*)alloc((size_t)D_MODEL * D_MODEL * 2);
    short* qkv  = (short*)alloc((size_t)3 * BHTD * 2);           // Q,K,V [B,H,T,D]
    short* ao   = (short*)alloc((size_t)M_ROWS * D_MODEL * 2);   // attn out bf16

    f32_to_bf16_k<<<dim3(M_ROWS * D_MODEL / (256 * 4)), dim3(256), 0, stream>>>(
        x, xb, M_ROWS * D_MODEL);
    transpose_pack_k<<<dim3(32, 32, 4), dim3(32, 8), 0, stream>>>(wq, wk, wv, wo, qkvT, woT);
    gemm128<0><<<dim3(M_ROWS / 128, 3 * D_MODEL / 128), dim3(256), 0, stream>>>(
        xb, qkvT, bq, bk, bv, qkv, nullptr, D_MODEL);
    attn_kernel<<<dim3(SEQ / 64, BATCH * NHEADS), dim3(256), 0, stream>>>(
        qkv, qkv + BHTD, qkv + 2 * BHTD, ao);
    gemm128<1><<<dim3(M_ROWS / 128, D_MODEL / 128), dim3(256), 0, stream>>>(
        ao, woT, bo, nullptr, nullptr, nullptr, out, D_MODEL);
}

// Round 2
// 260.816 us; speedup vs baseline: 2.1190x; 2.1190x over previous
//
#include <hip/hip_runtime.h>
#include <hip/hip_bf16.h>
#include <stdint.h>

#define D_MODEL 1024
#define NHEADS 16
#define HDIM 64
#define BATCH 4
#define SEQ 2048
#define M_ROWS (BATCH*SEQ)                     // 8192
#define BHTD ((size_t)BATCH*NHEADS*SEQ*HDIM)   // 8388608 elems

typedef __attribute__((ext_vector_type(8))) short bf16x8;
typedef __attribute__((ext_vector_type(4))) float f32x4;
typedef __attribute__((address_space(1))) uint32_t as1_u32;
typedef __attribute__((address_space(3))) uint32_t as3_u32;

__device__ __forceinline__ void gload_lds16(const void* g, void* l) {
    __builtin_amdgcn_global_load_lds((const as1_u32*)(uintptr_t)g,
                                     (as3_u32*)(uintptr_t)l, 16, 0, 0);
}

__device__ __forceinline__ short f2bf(float f) {
    __hip_bfloat16 h = __float2bfloat16(f);
    return *reinterpret_cast<short*>(&h);
}

// ---------------------------------------------------------------- conversions
__global__ void f32_to_bf16_k(const float* __restrict__ in, short* __restrict__ out, int n) {
    int i = (blockIdx.x * blockDim.x + threadIdx.x) * 4;
    if (i >= n) return;
    float4 v = *(const float4*)&in[i];
    short4 r;
    r.x = f2bf(v.x); r.y = f2bf(v.y); r.z = f2bf(v.z); r.w = f2bf(v.w);
    *(short4*)&out[i] = r;
}

// transpose 1024x1024 fp32 [k][n] -> bf16 [n][k]; z selects {wq,wk,wv,wo}
__global__ void transpose_pack_k(const float* __restrict__ wq, const float* __restrict__ wk,
                                 const float* __restrict__ wv, const float* __restrict__ wo,
                                 short* __restrict__ qkvT, short* __restrict__ woT) {
    __shared__ float tile[32][33];
    int z = blockIdx.z;
    const float* src = (z == 0) ? wq : (z == 1) ? wk : (z == 2) ? wv : wo;
    short* dst = (z < 3) ? (qkvT + (size_t)z * D_MODEL * D_MODEL) : woT;
    int bx = blockIdx.x, by = blockIdx.y;
    int tx = threadIdx.x, ty = threadIdx.y;
#pragma unroll
    for (int r = 0; r < 32; r += 8)
        tile[ty + r][tx] = src[(size_t)(by * 32 + ty + r) * D_MODEL + bx * 32 + tx];
    __syncthreads();
#pragma unroll
    for (int r = 0; r < 32; r += 8)
        dst[(size_t)(bx * 32 + ty + r) * D_MODEL + by * 32 + tx] = f2bf(tile[tx][ty + r]);
}

// ---------------------------------------------------------------- GEMM 128x128x32
template <int MODE>
__global__ __launch_bounds__(256) void gemm128(const short* __restrict__ A,
                                               const short* __restrict__ Bt,
                                               const float* __restrict__ b0,
                                               const float* __restrict__ b1,
                                               const float* __restrict__ b2,
                                               short* __restrict__ outb,
                                               float* __restrict__ outf,
                                               int K) {
    __shared__ short As[128 * 32];
    __shared__ short Bs[128 * 32];
    int tid = threadIdx.x;
    int lane = tid & 63, wid = tid >> 6;
    int wr = wid >> 1, wc = wid & 1;
    int lr = lane & 15, lg = lane >> 4;
    int mb = blockIdx.x * 128;
    int nb = blockIdx.y * 128;

    f32x4 acc[4][4] = {};
    int nk = K / 32;
    int r = tid >> 2, seg = tid & 3;
    for (int kt = 0; kt < nk; ++kt) {
        int kb = kt * 32;
        __syncthreads();
        const short* ga = A + (size_t)(mb + r) * K + kb + seg * 8;
        const short* gb = Bt + (size_t)(nb + r) * K + kb + seg * 8;
        gload_lds16(ga, &As[tid * 8]);
        gload_lds16(ga + (size_t)64 * K, &As[2048 + tid * 8]);
        gload_lds16(gb, &Bs[tid * 8]);
        gload_lds16(gb + (size_t)64 * K, &Bs[2048 + tid * 8]);
        __syncthreads();
        bf16x8 af[4], bfr[4];
#pragma unroll
        for (int ms = 0; ms < 4; ++ms)
            af[ms] = *(const bf16x8*)&As[(wr * 64 + ms * 16 + lr) * 32 + lg * 8];
#pragma unroll
        for (int ns = 0; ns < 4; ++ns)
            bfr[ns] = *(const bf16x8*)&Bs[(wc * 64 + ns * 16 + lr) * 32 + lg * 8];
#pragma unroll
        for (int ms = 0; ms < 4; ++ms)
#pragma unroll
            for (int ns = 0; ns < 4; ++ns)
                acc[ms][ns] = __builtin_amdgcn_mfma_f32_16x16x32_bf16(af[ms], bfr[ns], acc[ms][ns], 0, 0, 0);
    }
#pragma unroll
    for (int ms = 0; ms < 4; ++ms) {
        int row0 = mb + wr * 64 + ms * 16 + lg * 4;
#pragma unroll
        for (int ns = 0; ns < 4; ++ns) {
            int col = nb + wc * 64 + ns * 16 + lr;
            if (MODE == 0) {
                int sec = col >> 10;
                int nn = col & 1023;
                float bias = (sec == 0) ? b0[nn] : (sec == 1) ? b1[nn] : b2[nn];
                int h = nn >> 6, d = nn & 63;
#pragma unroll
                for (int j = 0; j < 4; ++j) {
                    int m = row0 + j;
                    int bb = m >> 11, t = m & 2047;
                    float v = acc[ms][ns][j] + bias;
                    if (sec == 0) v *= 0.125f;  // 1/sqrt(64) folded into Q
                    outb[(size_t)sec * BHTD + (((size_t)(bb * NHEADS + h)) * SEQ + t) * HDIM + d] = f2bf(v);
                }
            } else {
                float bias = b0[col];
#pragma unroll
                for (int j = 0; j < 4; ++j)
                    outf[(size_t)(row0 + j) * D_MODEL + col] = acc[ms][ns][j] + bias;
            }
        }
    }
}

// ---------------------------------------------------------------- flash attention v2
// 256 thr = 4 waves; wave owns 32 q rows (2x 16-row tiles); block = 128 q rows.
// Each block processes qb pair (p, 15-p): uniform 34 kv-iters -> perfect balance.
// KVBLK = 64. K staged via global_load_lds with pre-swizzled source cols;
// Vt (transposed) and Ps swizzled: short_idx = row*64 + (col ^ ((row&7)<<3)).
__global__ __launch_bounds__(256) void attn_kernel(const short* __restrict__ Q,
                                                   const short* __restrict__ Kb,
                                                   const short* __restrict__ Vb,
                                                   short* __restrict__ attn_out) {
    __shared__ short Ks[64 * 64];
    __shared__ short Vt[64 * 64];
    __shared__ short Ps[4 * 32 * 64];
    int tid = threadIdx.x, lane = tid & 63, w = tid >> 6;
    int lr = lane & 15, lg = lane >> 4;

    // bijective remap: all 8 qb-pair blocks of one bh land on one XCD (linear%8)
    int linear = blockIdx.x + 8 * blockIdx.y;   // gridDim = (8, 64)
    int bh = (linear & 7) * 8 + ((linear >> 3) & 7);
    int pairi = linear >> 6;                     // 0..7
    int b = bh >> 4, h = bh & 15;
    const short* Qp = Q + (size_t)bh * SEQ * HDIM;
    const short* Kp = Kb + (size_t)bh * SEQ * HDIM;
    const short* Vp = Vb + (size_t)bh * SEQ * HDIM;

    int krow0 = w * 16 + (lane >> 3);  // staging rows: batch si adds 8
    int kseg = lane & 7;

    for (int half = 0; half < 2; ++half) {
        int qb = half ? (15 - pairi) : pairi;
        int qbase = qb * 128;
        int rowmax = qbase + w * 32 + 31;

        bf16x8 qf[2][2];
#pragma unroll
        for (int mt = 0; mt < 2; ++mt)
#pragma unroll
            for (int kp = 0; kp < 2; ++kp)
                qf[mt][kp] = *(const bf16x8*)&Qp[(size_t)(qbase + w * 32 + mt * 16 + lr) * HDIM + kp * 32 + lg * 8];

        f32x4 o[2][4] = {};
        float mred[2][4], lred[2][4];
#pragma unroll
        for (int mt = 0; mt < 2; ++mt)
#pragma unroll
            for (int j = 0; j < 4; ++j) { mred[mt][j] = -3e38f; lred[mt][j] = 0.f; }

        int nkb = (qbase + 128) >> 6;   // 2*qb+2
        for (int kvb = 0; kvb < nkb; ++kvb) {
            int tb = kvb * 64;
            __syncthreads();
            // --- stage K [64][64] swizzled, via direct-to-LDS (linear dest, swizzled src)
#pragma unroll
            for (int si = 0; si < 2; ++si) {
                int row = krow0 + si * 8;
                int sp = kseg ^ (row & 7);
                gload_lds16(Kp + (size_t)(tb + row) * HDIM + sp * 8, &Ks[row * 64 + kseg * 8]);
            }
            // --- stage V transposed [d][kv] swizzled, via regs
#pragma unroll
            for (int si = 0; si < 2; ++si) {
                int row = krow0 + si * 8;
                bf16x8 v = *(const bf16x8*)&Vp[(size_t)(tb + row) * HDIM + kseg * 8];
#pragma unroll
                for (int j = 0; j < 8; ++j) {
                    int d = kseg * 8 + j;                 // d&7 == j
                    Vt[d * 64 + (row ^ (j << 3))] = v[j];
                }
            }
            __syncthreads();

            if (tb <= rowmax) {
#pragma unroll
                for (int mt = 0; mt < 2; ++mt) {
                    // --- S = Q K^T (16 q rows x 64 kv)
                    f32x4 sacc[4] = {};
                    __builtin_amdgcn_s_setprio(1);
#pragma unroll
                    for (int nt = 0; nt < 4; ++nt) {
                        int krow = nt * 16 + lr;
#pragma unroll
                        for (int kp = 0; kp < 2; ++kp) {
                            bf16x8 kf = *(const bf16x8*)&Ks[krow * 64 + ((kp * 32 + lg * 8) ^ ((krow & 7) << 3))];
                            sacc[nt] = __builtin_amdgcn_mfma_f32_16x16x32_bf16(qf[mt][kp], kf, sacc[nt], 0, 0, 0);
                        }
                    }
                    __builtin_amdgcn_s_setprio(0);
                    // --- online softmax; rows live in 16-lane groups (fixed lg)
                    float al[4];
#pragma unroll
                    for (int j = 0; j < 4; ++j) {
                        int qg = qbase + w * 32 + mt * 16 + lg * 4 + j;
                        float x[4];
#pragma unroll
                        for (int nt = 0; nt < 4; ++nt) {
                            int kvi = tb + nt * 16 + lr;
                            x[nt] = (kvi <= qg) ? sacc[nt][j] : -3e38f;
                        }
                        float mv = fmaxf(fmaxf(x[0], x[1]), fmaxf(x[2], x[3]));
                        mv = fmaxf(mv, __shfl_xor(mv, 1));
                        mv = fmaxf(mv, __shfl_xor(mv, 2));
                        mv = fmaxf(mv, __shfl_xor(mv, 4));
                        mv = fmaxf(mv, __shfl_xor(mv, 8));
                        float mo = mred[mt][j];
                        float mn = fmaxf(mo, mv);
                        float a = __expf(mo - mn);
                        mred[mt][j] = mn;
                        float p[4], ps = 0.f;
#pragma unroll
                        for (int nt = 0; nt < 4; ++nt) { p[nt] = __expf(x[nt] - mn); ps += p[nt]; }
                        ps += __shfl_xor(ps, 1);
                        ps += __shfl_xor(ps, 2);
                        ps += __shfl_xor(ps, 4);
                        ps += __shfl_xor(ps, 8);
                        lred[mt][j] = lred[mt][j] * a + ps;
                        al[j] = a;
                        int pr = mt * 16 + lg * 4 + j;
#pragma unroll
                        for (int nt = 0; nt < 4; ++nt)
                            Ps[w * 2048 + pr * 64 + ((nt * 16 + lr) ^ ((pr & 7) << 3))] = f2bf(p[nt]);
                    }
                    // rescale O
#pragma unroll
                    for (int dt = 0; dt < 4; ++dt)
#pragma unroll
                        for (int j = 0; j < 4; ++j) o[mt][dt][j] *= al[j];
                    // --- PV
                    bf16x8 pf[2];
                    int prow = mt * 16 + lr;
#pragma unroll
                    for (int kp = 0; kp < 2; ++kp)
                        pf[kp] = *(const bf16x8*)&Ps[w * 2048 + prow * 64 + ((kp * 32 + lg * 8) ^ ((prow & 7) << 3))];
                    __builtin_amdgcn_s_setprio(1);
#pragma unroll
                    for (int dt = 0; dt < 4; ++dt) {
                        int vr = dt * 16 + lr;
#pragma unroll
                        for (int kp = 0; kp < 2; ++kp) {
                            bf16x8 vf = *(const bf16x8*)&Vt[vr * 64 + ((kp * 32 + lg * 8) ^ ((vr & 7) << 3))];
                            o[mt][dt] = __builtin_amdgcn_mfma_f32_16x16x32_bf16(pf[kp], vf, o[mt][dt], 0, 0, 0);
                        }
                    }
                    __builtin_amdgcn_s_setprio(0);
                }
            }
        }
        // --- epilogue for this half
#pragma unroll
        for (int mt = 0; mt < 2; ++mt) {
            float inv[4];
#pragma unroll
            for (int j = 0; j < 4; ++j) inv[j] = 1.0f / lred[mt][j];
#pragma unroll
            for (int dt = 0; dt < 4; ++dt)
#pragma unroll
                for (int j = 0; j < 4; ++j) {
                    int qg = qbase + w * 32 + mt * 16 + lg * 4 + j;
                    attn_out[((size_t)(b * SEQ) + qg) * D_MODEL + h * HDIM + dt * 16 + lr] =
                        f2bf(o[mt][dt][j] * inv[j]);
                }
        }
    }
}

// ---------------------------------------------------------------- launch
extern "C" void kernel_launch(void* const* d_in, const int* in_sizes, int n_in,
                              void* d_out, int out_size, void* d_ws, size_t ws_size,
                              hipStream_t stream) {
    const float* x  = (const float*)d_in[0];
    const float* wq = (const float*)d_in[1];
    const float* bq = (const float*)d_in[2];
    const float* wk = (const float*)d_in[3];
    const float* bk = (const float*)d_in[4];
    const float* wv = (const float*)d_in[5];
    const float* bv = (const float*)d_in[6];
    const float* wo = (const float*)d_in[7];
    const float* bo = (const float*)d_in[8];
    float* out = (float*)d_out;

    char* ws = (char*)d_ws;
    size_t off = 0;
    auto alloc = [&](size_t bytes) {
        void* p = ws + off;
        off += (bytes + 255) & ~(size_t)255;
        return p;
    };
    short* xb   = (short*)alloc((size_t)M_ROWS * D_MODEL * 2);
    short* qkvT = (short*)alloc((size_t)3 * D_MODEL * D_MODEL * 2);
    short* woT  = (short*)alloc((size_t)D_MODEL * D_MODEL * 2);
    short* qkv  = (short*)alloc((size_t)3 * BHTD * 2);
    short* ao   = (short*)alloc((size_t)M_ROWS * D_MODEL * 2);

    f32_to_bf16_k<<<dim3(M_ROWS * D_MODEL / (256 * 4)), dim3(256), 0, stream>>>(
        x, xb, M_ROWS * D_MODEL);
    transpose_pack_k<<<dim3(32, 32, 4), dim3(32, 8), 0, stream>>>(wq, wk, wv, wo, qkvT, woT);
    gemm128<0><<<dim3(M_ROWS / 128, 3 * D_MODEL / 128), dim3(256), 0, stream>>>(
        xb, qkvT, bq, bk, bv, qkv, nullptr, D_MODEL);
    attn_kernel<<<dim3(8, 64), dim3(256), 0, stream>>>(
        qkv, qkv + BHTD, qkv + 2 * BHTD, ao);
    gemm128<1><<<dim3(M_ROWS / 128, D_MODEL / 128), dim3(256), 0, stream>>>(
        ao, woT, bo, nullptr, nullptr, nullptr, out, D_MODEL);
}

// Round 3
// 241.591 us; speedup vs baseline: 2.2876x; 1.0796x over previous
//
#include <hip/hip_runtime.h>
#include <hip/hip_bf16.h>
#include <stdint.h>

#define D_MODEL 1024
#define NHEADS 16
#define HDIM 64
#define BATCH 4
#define SEQ 2048
#define M_ROWS (BATCH*SEQ)                     // 8192
#define BHTD ((size_t)BATCH*NHEADS*SEQ*HDIM)   // 8388608 elems

typedef __attribute__((ext_vector_type(8))) short bf16x8;
typedef __attribute__((ext_vector_type(4))) float f32x4;
typedef __attribute__((address_space(1))) uint32_t as1_u32;
typedef __attribute__((address_space(3))) uint32_t as3_u32;

__device__ __forceinline__ void gload_lds16(const void* g, void* l) {
    __builtin_amdgcn_global_load_lds((const as1_u32*)(uintptr_t)g,
                                     (as3_u32*)(uintptr_t)l, 16, 0, 0);
}

__device__ __forceinline__ short f2bf(float f) {
    __hip_bfloat16 h = __float2bfloat16(f);
    return *reinterpret_cast<short*>(&h);
}

// ---------------------------------------------------------------- conversions
__global__ void f32_to_bf16_k(const float* __restrict__ in, short* __restrict__ out, int n) {
    int i = (blockIdx.x * blockDim.x + threadIdx.x) * 4;
    if (i >= n) return;
    float4 v = *(const float4*)&in[i];
    short4 r;
    r.x = f2bf(v.x); r.y = f2bf(v.y); r.z = f2bf(v.z); r.w = f2bf(v.w);
    *(short4*)&out[i] = r;
}

// transpose 1024x1024 fp32 [k][n] -> bf16 [n][k]; z selects {wq,wk,wv,wo}
__global__ void transpose_pack_k(const float* __restrict__ wq, const float* __restrict__ wk,
                                 const float* __restrict__ wv, const float* __restrict__ wo,
                                 short* __restrict__ qkvT, short* __restrict__ woT) {
    __shared__ float tile[32][33];
    int z = blockIdx.z;
    const float* src = (z == 0) ? wq : (z == 1) ? wk : (z == 2) ? wv : wo;
    short* dst = (z < 3) ? (qkvT + (size_t)z * D_MODEL * D_MODEL) : woT;
    int bx = blockIdx.x, by = blockIdx.y;
    int tx = threadIdx.x, ty = threadIdx.y;
#pragma unroll
    for (int r = 0; r < 32; r += 8)
        tile[ty + r][tx] = src[(size_t)(by * 32 + ty + r) * D_MODEL + bx * 32 + tx];
    __syncthreads();
#pragma unroll
    for (int r = 0; r < 32; r += 8)
        dst[(size_t)(bx * 32 + ty + r) * D_MODEL + by * 32 + tx] = f2bf(tile[tx][ty + r]);
}

// V [bh][t][d] bf16 -> Vt [bh][d][t] bf16, 64x64 tiles, swizzled LDS
__global__ __launch_bounds__(256) void vt_transpose_k(const short* __restrict__ V,
                                                      short* __restrict__ Vt) {
    __shared__ short Vsw[64 * 64];
    int tid = threadIdx.x;
    int t0 = blockIdx.x * 64;
    int bh = blockIdx.y;
    const short* Vp = V + ((size_t)bh * SEQ + t0) * HDIM;
    {
        int row = tid >> 2;
#pragma unroll
        for (int i = 0; i < 2; ++i) {
            int c = (tid & 3) * 2 + i;
            bf16x8 v = *(const bf16x8*)&Vp[(size_t)row * HDIM + c * 8];
            *(bf16x8*)&Vsw[row * 64 + ((c ^ (row & 7)) * 8)] = v;
        }
    }
    __syncthreads();
    {
        int d = tid >> 2, tc = tid & 3;
        short vals[16];
#pragma unroll
        for (int s = 0; s < 16; ++s) {
            int t = tc * 16 + s;
            vals[s] = Vsw[t * 64 + (((d >> 3) ^ (t & 7)) * 8) + (d & 7)];
        }
        short* outp = &Vt[((size_t)bh * HDIM + d) * SEQ + t0 + tc * 16];
        *(bf16x8*)&outp[0] = *(bf16x8*)&vals[0];
        *(bf16x8*)&outp[8] = *(bf16x8*)&vals[8];
    }
}

// ---------------------------------------------------------------- GEMM 128x128x32
template <int MODE>
__global__ __launch_bounds__(256) void gemm128(const short* __restrict__ A,
                                               const short* __restrict__ Bt,
                                               const float* __restrict__ b0,
                                               const float* __restrict__ b1,
                                               const float* __restrict__ b2,
                                               short* __restrict__ outb,
                                               float* __restrict__ outf,
                                               int K) {
    __shared__ short As[128 * 32];
    __shared__ short Bs[128 * 32];
    int tid = threadIdx.x;
    int lane = tid & 63, wid = tid >> 6;
    int wr = wid >> 1, wc = wid & 1;
    int lr = lane & 15, lg = lane >> 4;
    int mb = blockIdx.x * 128;
    int nb = blockIdx.y * 128;

    f32x4 acc[4][4] = {};
    int nk = K / 32;
    int r = tid >> 2, seg = tid & 3;
    for (int kt = 0; kt < nk; ++kt) {
        int kb = kt * 32;
        __syncthreads();
        const short* ga = A + (size_t)(mb + r) * K + kb + seg * 8;
        const short* gb = Bt + (size_t)(nb + r) * K + kb + seg * 8;
        gload_lds16(ga, &As[tid * 8]);
        gload_lds16(ga + (size_t)64 * K, &As[2048 + tid * 8]);
        gload_lds16(gb, &Bs[tid * 8]);
        gload_lds16(gb + (size_t)64 * K, &Bs[2048 + tid * 8]);
        __syncthreads();
        bf16x8 af[4], bfr[4];
#pragma unroll
        for (int ms = 0; ms < 4; ++ms)
            af[ms] = *(const bf16x8*)&As[(wr * 64 + ms * 16 + lr) * 32 + lg * 8];
#pragma unroll
        for (int ns = 0; ns < 4; ++ns)
            bfr[ns] = *(const bf16x8*)&Bs[(wc * 64 + ns * 16 + lr) * 32 + lg * 8];
#pragma unroll
        for (int ms = 0; ms < 4; ++ms)
#pragma unroll
            for (int ns = 0; ns < 4; ++ns)
                acc[ms][ns] = __builtin_amdgcn_mfma_f32_16x16x32_bf16(af[ms], bfr[ns], acc[ms][ns], 0, 0, 0);
    }
#pragma unroll
    for (int ms = 0; ms < 4; ++ms) {
        int row0 = mb + wr * 64 + ms * 16 + lg * 4;
#pragma unroll
        for (int ns = 0; ns < 4; ++ns) {
            int col = nb + wc * 64 + ns * 16 + lr;
            if (MODE == 0) {
                int sec = col >> 10;
                int nn = col & 1023;
                float bias = (sec == 0) ? b0[nn] : (sec == 1) ? b1[nn] : b2[nn];
                int h = nn >> 6, d = nn & 63;
#pragma unroll
                for (int j = 0; j < 4; ++j) {
                    int m = row0 + j;
                    int bb = m >> 11, t = m & 2047;
                    float v = acc[ms][ns][j] + bias;
                    if (sec == 0) v *= 0.18033689f;  // 1/sqrt(64) * log2(e) folded into Q
                    outb[(size_t)sec * BHTD + (((size_t)(bb * NHEADS + h)) * SEQ + t) * HDIM + d] = f2bf(v);
                }
            } else {
                float bias = b0[col];
#pragma unroll
                for (int j = 0; j < 4; ++j)
                    outf[(size_t)(row0 + j) * D_MODEL + col] = acc[ms][ns][j] + bias;
            }
        }
    }
}

// ---------------------------------------------------------------- flash attention v3
// 1024 blocks, 256 thr = 4 waves; block owns 64 q rows (wave = 16); pairs (p,31-p).
// KVBLK=64, K and V^T both staged via swizzled global_load_lds, double-buffered.
// Q pre-scaled by log2(e)/sqrt(64); softmax in exp2 domain.
__global__ __launch_bounds__(256) void attn_kernel(const short* __restrict__ Q,
                                                   const short* __restrict__ Kb,
                                                   const short* __restrict__ VTg,
                                                   short* __restrict__ attn_out) {
    __shared__ short Ks[2][4096];
    __shared__ short Vt[2][4096];
    __shared__ short Ps[4][1024];
    int tid = threadIdx.x, lane = tid & 63, w = tid >> 6;
    int lr = lane & 15, lg = lane >> 4;

    // bijective: all 16 blocks of one bh on one XCD (linear%8)
    int linear = blockIdx.x + 8 * blockIdx.y;   // gridDim (8,128) -> 0..1023
    int idx = linear >> 3;                       // 0..127
    int bh = (linear & 7) * 8 + (idx & 7);
    int p = idx >> 3;                            // 0..15
    int b = bh >> 4, h = bh & 15;
    const short* Qp = Q + (size_t)bh * SEQ * HDIM;
    const short* Kp = Kb + (size_t)bh * SEQ * HDIM;
    const short* VTp = VTg + (size_t)bh * HDIM * SEQ;

    int krow0 = w * 16 + (lane >> 3);  // staging rows; si adds 8
    int kseg = lane & 7;
    int sp = kseg ^ (lane >> 3);       // pre-swizzled source chunk (row&7 == lane>>3)

    int buf = 0;
    for (int half = 0; half < 2; ++half) {
        int qb = half ? (31 - p) : p;
        int qbase = qb << 6;
        int qrow = qbase + w * 16;

        bf16x8 qf[2];
        qf[0] = *(const bf16x8*)&Qp[(size_t)(qrow + lr) * HDIM + lg * 8];
        qf[1] = *(const bf16x8*)&Qp[(size_t)(qrow + lr) * HDIM + 32 + lg * 8];

        f32x4 o[4] = {};
        float m[4], l[4];
#pragma unroll
        for (int j = 0; j < 4; ++j) { m[j] = -3e38f; l[j] = 0.f; }

        int nkb = qb + 1;
        // prologue: stage tile 0 into current buf
        {
            int tb = 0;
#pragma unroll
            for (int si = 0; si < 2; ++si) {
                int row = krow0 + si * 8;
                gload_lds16(Kp + (size_t)(tb + row) * HDIM + sp * 8, &Ks[buf][row * 64 + kseg * 8]);
                gload_lds16(VTp + (size_t)row * SEQ + tb + sp * 8, &Vt[buf][row * 64 + kseg * 8]);
            }
        }
        for (int kvb = 0; kvb < nkb; ++kvb) {
            int tb = kvb << 6;
            __syncthreads();   // drains stage(kvb); frees buf^1
            if (kvb + 1 < nkb) {
                int tb2 = tb + 64;
                int bn = buf ^ 1;
#pragma unroll
                for (int si = 0; si < 2; ++si) {
                    int row = krow0 + si * 8;
                    gload_lds16(Kp + (size_t)(tb2 + row) * HDIM + sp * 8, &Ks[bn][row * 64 + kseg * 8]);
                    gload_lds16(VTp + (size_t)row * SEQ + tb2 + sp * 8, &Vt[bn][row * 64 + kseg * 8]);
                }
            }
            // ---- QK^T
            f32x4 sacc[4] = {};
            const short* ksb = &Ks[buf][0];
            __builtin_amdgcn_s_setprio(1);
#pragma unroll
            for (int nt = 0; nt < 4; ++nt) {
                int krow = nt * 16 + lr;
                int sw = (krow & 7) << 3;
#pragma unroll
                for (int kp = 0; kp < 2; ++kp) {
                    bf16x8 kf = *(const bf16x8*)&ksb[krow * 64 + ((kp * 32 + lg * 8) ^ sw)];
                    sacc[nt] = __builtin_amdgcn_mfma_f32_16x16x32_bf16(qf[kp], kf, sacc[nt], 0, 0, 0);
                }
            }
            __builtin_amdgcn_s_setprio(0);
            // ---- online softmax (exp2 domain), mask only on diagonal tile
            bool lastt = (kvb == nkb - 1);
            float al[4];
#pragma unroll
            for (int j = 0; j < 4; ++j) {
                int qg = qrow + lg * 4 + j;
                float x0 = sacc[0][j], x1 = sacc[1][j], x2 = sacc[2][j], x3 = sacc[3][j];
                if (lastt) {
                    if (tb +      lr > qg) x0 = -3e38f;
                    if (tb + 16 + lr > qg) x1 = -3e38f;
                    if (tb + 32 + lr > qg) x2 = -3e38f;
                    if (tb + 48 + lr > qg) x3 = -3e38f;
                }
                float mv = fmaxf(fmaxf(x0, x1), fmaxf(x2, x3));
                mv = fmaxf(mv, __shfl_xor(mv, 1));
                mv = fmaxf(mv, __shfl_xor(mv, 2));
                mv = fmaxf(mv, __shfl_xor(mv, 4));
                mv = fmaxf(mv, __shfl_xor(mv, 8));
                float mo = m[j];
                float mn = fmaxf(mo, mv);
                m[j] = mn;
                float a = exp2f(mo - mn);
                float p0 = exp2f(x0 - mn), p1 = exp2f(x1 - mn);
                float p2 = exp2f(x2 - mn), p3 = exp2f(x3 - mn);
                float ps = (p0 + p1) + (p2 + p3);
                ps += __shfl_xor(ps, 1);
                ps += __shfl_xor(ps, 2);
                ps += __shfl_xor(ps, 4);
                ps += __shfl_xor(ps, 8);
                l[j] = l[j] * a + ps;
                al[j] = a;
                int pr = lg * 4 + j;
                int psw = (pr & 7) << 3;
                short* pb = &Ps[w][pr * 64];
                pb[(lr)      ^ psw] = f2bf(p0);
                pb[(16 + lr) ^ psw] = f2bf(p1);
                pb[(32 + lr) ^ psw] = f2bf(p2);
                pb[(48 + lr) ^ psw] = f2bf(p3);
            }
#pragma unroll
            for (int dt = 0; dt < 4; ++dt)
#pragma unroll
                for (int j = 0; j < 4; ++j) o[dt][j] *= al[j];
            // ---- PV
            bf16x8 pf[2];
            {
                int sw = (lr & 7) << 3;
                pf[0] = *(const bf16x8*)&Ps[w][lr * 64 + ((lg * 8) ^ sw)];
                pf[1] = *(const bf16x8*)&Ps[w][lr * 64 + ((32 + lg * 8) ^ sw)];
            }
            const short* vtb = &Vt[buf][0];
            __builtin_amdgcn_s_setprio(1);
#pragma unroll
            for (int dt = 0; dt < 4; ++dt) {
                int vr = dt * 16 + lr;
                int sw = (vr & 7) << 3;
#pragma unroll
                for (int kp = 0; kp < 2; ++kp) {
                    bf16x8 vf = *(const bf16x8*)&vtb[vr * 64 + ((kp * 32 + lg * 8) ^ sw)];
                    o[dt] = __builtin_amdgcn_mfma_f32_16x16x32_bf16(pf[kp], vf, o[dt], 0, 0, 0);
                }
            }
            __builtin_amdgcn_s_setprio(0);
            buf ^= 1;
        }
        // ---- epilogue
        float inv[4];
#pragma unroll
        for (int j = 0; j < 4; ++j) inv[j] = 1.0f / l[j];
#pragma unroll
        for (int dt = 0; dt < 4; ++dt)
#pragma unroll
            for (int j = 0; j < 4; ++j) {
                int qg = qrow + lg * 4 + j;
                attn_out[((size_t)(b * SEQ) + qg) * D_MODEL + h * HDIM + dt * 16 + lr] =
                    f2bf(o[dt][j] * inv[j]);
            }
    }
}

// ---------------------------------------------------------------- launch
extern "C" void kernel_launch(void* const* d_in, const int* in_sizes, int n_in,
                              void* d_out, int out_size, void* d_ws, size_t ws_size,
                              hipStream_t stream) {
    const float* x  = (const float*)d_in[0];
    const float* wq = (const float*)d_in[1];
    const float* bq = (const float*)d_in[2];
    const float* wk = (const float*)d_in[3];
    const float* bk = (const float*)d_in[4];
    const float* wv = (const float*)d_in[5];
    const float* bv = (const float*)d_in[6];
    const float* wo = (const float*)d_in[7];
    const float* bo = (const float*)d_in[8];
    float* out = (float*)d_out;

    char* ws = (char*)d_ws;
    size_t off = 0;
    auto alloc = [&](size_t bytes) {
        void* p = ws + off;
        off += (bytes + 255) & ~(size_t)255;
        return p;
    };
    short* xb   = (short*)alloc((size_t)M_ROWS * D_MODEL * 2);
    short* qkvT = (short*)alloc((size_t)3 * D_MODEL * D_MODEL * 2);
    short* woT  = (short*)alloc((size_t)D_MODEL * D_MODEL * 2);
    short* qkv  = (short*)alloc((size_t)3 * BHTD * 2);
    short* ao   = (short*)alloc((size_t)M_ROWS * D_MODEL * 2);
    short* vt_g = xb;   // xb dead after QKV GEMM; exact size match (16.7MB)

    f32_to_bf16_k<<<dim3(M_ROWS * D_MODEL / (256 * 4)), dim3(256), 0, stream>>>(
        x, xb, M_ROWS * D_MODEL);
    transpose_pack_k<<<dim3(32, 32, 4), dim3(32, 8), 0, stream>>>(wq, wk, wv, wo, qkvT, woT);
    gemm128<0><<<dim3(M_ROWS / 128, 3 * D_MODEL / 128), dim3(256), 0, stream>>>(
        xb, qkvT, bq, bk, bv, qkv, nullptr, D_MODEL);
    vt_transpose_k<<<dim3(SEQ / 64, BATCH * NHEADS), dim3(256), 0, stream>>>(
        qkv + 2 * BHTD, vt_g);
    attn_kernel<<<dim3(8, 128), dim3(256), 0, stream>>>(
        qkv, qkv + BHTD, vt_g, ao);
    gemm128<1><<<dim3(M_ROWS / 128, D_MODEL / 128), dim3(256), 0, stream>>>(
        ao, woT, bo, nullptr, nullptr, nullptr, out, D_MODEL);
}

// Round 4
// 202.416 us; speedup vs baseline: 2.7303x; 1.1935x over previous
//
#include <hip/hip_runtime.h>
#include <hip/hip_bf16.h>
#include <stdint.h>

#define D_MODEL 1024
#define NHEADS 16
#define HDIM 64
#define BATCH 4
#define SEQ 2048
#define M_ROWS (BATCH*SEQ)                     // 8192
#define BHTD ((size_t)BATCH*NHEADS*SEQ*HDIM)   // 8388608 elems

typedef __attribute__((ext_vector_type(8))) short bf16x8;
typedef __attribute__((ext_vector_type(4))) float f32x4;
typedef __attribute__((ext_vector_type(16))) float f32x16;
typedef __attribute__((address_space(1))) uint32_t as1_u32;
typedef __attribute__((address_space(3))) uint32_t as3_u32;

__device__ __forceinline__ void gload_lds16(const void* g, void* l) {
    __builtin_amdgcn_global_load_lds((const as1_u32*)(uintptr_t)g,
                                     (as3_u32*)(uintptr_t)l, 16, 0, 0);
}

__device__ __forceinline__ short f2bf(float f) {
    __hip_bfloat16 h = __float2bfloat16(f);
    return *reinterpret_cast<short*>(&h);
}

__device__ __forceinline__ uint32_t cvtpk_bf16(float lo, float hi) {
    uint32_t r;
    asm("v_cvt_pk_bf16_f32 %0, %1, %2" : "=v"(r) : "v"(lo), "v"(hi));
    return r;
}

// ---------------------------------------------------------------- conversions
__global__ void f32_to_bf16_k(const float* __restrict__ in, short* __restrict__ out, int n) {
    int i = (blockIdx.x * blockDim.x + threadIdx.x) * 4;
    if (i >= n) return;
    float4 v = *(const float4*)&in[i];
    short4 r;
    r.x = f2bf(v.x); r.y = f2bf(v.y); r.z = f2bf(v.z); r.w = f2bf(v.w);
    *(short4*)&out[i] = r;
}

// transpose 1024x1024 fp32 [k][n] -> bf16 [n][k]; z selects {wq,wk,wv,wo}
__global__ void transpose_pack_k(const float* __restrict__ wq, const float* __restrict__ wk,
                                 const float* __restrict__ wv, const float* __restrict__ wo,
                                 short* __restrict__ qkvT, short* __restrict__ woT) {
    __shared__ float tile[32][33];
    int z = blockIdx.z;
    const float* src = (z == 0) ? wq : (z == 1) ? wk : (z == 2) ? wv : wo;
    short* dst = (z < 3) ? (qkvT + (size_t)z * D_MODEL * D_MODEL) : woT;
    int bx = blockIdx.x, by = blockIdx.y;
    int tx = threadIdx.x, ty = threadIdx.y;
#pragma unroll
    for (int r = 0; r < 32; r += 8)
        tile[ty + r][tx] = src[(size_t)(by * 32 + ty + r) * D_MODEL + bx * 32 + tx];
    __syncthreads();
#pragma unroll
    for (int r = 0; r < 32; r += 8)
        dst[(size_t)(bx * 32 + ty + r) * D_MODEL + by * 32 + tx] = f2bf(tile[tx][ty + r]);
}

// V [bh][t][d] bf16 -> Vt [bh][d][t] bf16, 64x64 tiles, swizzled LDS
__global__ __launch_bounds__(256) void vt_transpose_k(const short* __restrict__ V,
                                                      short* __restrict__ Vt) {
    __shared__ short Vsw[64 * 64];
    int tid = threadIdx.x;
    int t0 = blockIdx.x * 64;
    int bh = blockIdx.y;
    const short* Vp = V + ((size_t)bh * SEQ + t0) * HDIM;
    {
        int row = tid >> 2;
#pragma unroll
        for (int i = 0; i < 2; ++i) {
            int c = (tid & 3) * 2 + i;
            bf16x8 v = *(const bf16x8*)&Vp[(size_t)row * HDIM + c * 8];
            *(bf16x8*)&Vsw[row * 64 + ((c ^ (row & 7)) * 8)] = v;
        }
    }
    __syncthreads();
    {
        int d = tid >> 2, tc = tid & 3;
        short vals[16];
#pragma unroll
        for (int s = 0; s < 16; ++s) {
            int t = tc * 16 + s;
            vals[s] = Vsw[t * 64 + (((d >> 3) ^ (t & 7)) * 8) + (d & 7)];
        }
        short* outp = &Vt[((size_t)bh * HDIM + d) * SEQ + t0 + tc * 16];
        *(bf16x8*)&outp[0] = *(bf16x8*)&vals[0];
        *(bf16x8*)&outp[8] = *(bf16x8*)&vals[8];
    }
}

// ---------------------------------------------------------------- GEMM 128x128x32
template <int MODE>
__global__ __launch_bounds__(256) void gemm128(const short* __restrict__ A,
                                               const short* __restrict__ Bt,
                                               const float* __restrict__ b0,
                                               const float* __restrict__ b1,
                                               const float* __restrict__ b2,
                                               short* __restrict__ outb,
                                               float* __restrict__ outf,
                                               int K) {
    __shared__ short As[128 * 32];
    __shared__ short Bs[128 * 32];
    int tid = threadIdx.x;
    int lane = tid & 63, wid = tid >> 6;
    int wr = wid >> 1, wc = wid & 1;
    int lr = lane & 15, lg = lane >> 4;
    int mb = blockIdx.x * 128;
    int nb = blockIdx.y * 128;

    f32x4 acc[4][4] = {};
    int nk = K / 32;
    int r = tid >> 2, seg = tid & 3;
    for (int kt = 0; kt < nk; ++kt) {
        int kb = kt * 32;
        __syncthreads();
        const short* ga = A + (size_t)(mb + r) * K + kb + seg * 8;
        const short* gb = Bt + (size_t)(nb + r) * K + kb + seg * 8;
        gload_lds16(ga, &As[tid * 8]);
        gload_lds16(ga + (size_t)64 * K, &As[2048 + tid * 8]);
        gload_lds16(gb, &Bs[tid * 8]);
        gload_lds16(gb + (size_t)64 * K, &Bs[2048 + tid * 8]);
        __syncthreads();
        bf16x8 af[4], bfr[4];
#pragma unroll
        for (int ms = 0; ms < 4; ++ms)
            af[ms] = *(const bf16x8*)&As[(wr * 64 + ms * 16 + lr) * 32 + lg * 8];
#pragma unroll
        for (int ns = 0; ns < 4; ++ns)
            bfr[ns] = *(const bf16x8*)&Bs[(wc * 64 + ns * 16 + lr) * 32 + lg * 8];
#pragma unroll
        for (int ms = 0; ms < 4; ++ms)
#pragma unroll
            for (int ns = 0; ns < 4; ++ns)
                acc[ms][ns] = __builtin_amdgcn_mfma_f32_16x16x32_bf16(af[ms], bfr[ns], acc[ms][ns], 0, 0, 0);
    }
#pragma unroll
    for (int ms = 0; ms < 4; ++ms) {
        int row0 = mb + wr * 64 + ms * 16 + lg * 4;
#pragma unroll
        for (int ns = 0; ns < 4; ++ns) {
            int col = nb + wc * 64 + ns * 16 + lr;
            if (MODE == 0) {
                int sec = col >> 10;
                int nn = col & 1023;
                float bias = (sec == 0) ? b0[nn] : (sec == 1) ? b1[nn] : b2[nn];
                int h = nn >> 6, d = nn & 63;
#pragma unroll
                for (int j = 0; j < 4; ++j) {
                    int m = row0 + j;
                    int bb = m >> 11, t = m & 2047;
                    float v = acc[ms][ns][j] + bias;
                    if (sec == 0) v *= 0.18033689f;  // 1/sqrt(64) * log2(e) folded into Q
                    outb[(size_t)sec * BHTD + (((size_t)(bb * NHEADS + h)) * SEQ + t) * HDIM + d] = f2bf(v);
                }
            } else {
                float bias = b0[col];
#pragma unroll
                for (int j = 0; j < 4; ++j)
                    outf[(size_t)(row0 + j) * D_MODEL + col] = acc[ms][ns][j] + bias;
            }
        }
    }
}

// ---------------------------------------------------------------- flash attention v4
// Swapped-operand structure: S^T = K.Q^T and O^T = V^T.P^T via mfma_32x32x16 so
// q lives on the lane axis (col=lane&31) for S, softmax stats, and O — softmax is
// in-lane + one shfl_xor(32); P assembled in-register via cvt_pk + 8 shuffles.
// 2 waves x 32 q rows = 64 q/block; pairs (p, 31-p) -> 33 uniform kv-iters.
// KVBLK=64; K and V^T staged via swizzled global_load_lds, double-buffered.
// Q pre-scaled by log2(e)/sqrt(64); softmax in exp2 domain; defer-max THR=10.
__global__ __launch_bounds__(128, 2) void attn_kernel(const short* __restrict__ Q,
                                                      const short* __restrict__ Kb,
                                                      const short* __restrict__ VTg,
                                                      short* __restrict__ attn_out) {
    __shared__ short Ks[2][4096];
    __shared__ short Vt[2][4096];
    int tid = threadIdx.x, lane = tid & 63, w = tid >> 6;
    int l31 = lane & 31, hi = lane >> 5;

    // bijective remap: all 16 blocks of one bh on one XCD (linear%8)
    int linear = blockIdx.x + 8 * blockIdx.y;   // gridDim (8,128) -> 0..1023
    int bh = (linear & 7) * 8 + ((linear >> 3) & 7);
    int pp = linear >> 6;                        // 0..15
    int b = bh >> 4, h = bh & 15;
    const short* Qp  = Q   + (size_t)bh * SEQ * HDIM;
    const short* Kp  = Kb  + (size_t)bh * SEQ * HDIM;
    const short* VTp = VTg + (size_t)bh * HDIM * SEQ;

    int srow = tid >> 3;            // 0..15 staging row base
    int kseg = tid & 7;
    int sp   = kseg ^ (srow & 7);   // pre-swizzled global chunk
    int swl  = (l31 & 7) << 3;      // frag-read swizzle

    int buf = 0;
    for (int half = 0; half < 2; ++half) {
        int qb = half ? (31 - pp) : pp;
        int qbase = qb << 6;
        int qrow0 = qbase + w * 32;
        int myq = qrow0 + l31;

        bf16x8 qf[4];
#pragma unroll
        for (int ks = 0; ks < 4; ++ks)
            qf[ks] = *(const bf16x8*)&Qp[(size_t)myq * HDIM + ks * 16 + hi * 8];

        f32x16 o0 = {}, o1 = {};
        float m = -3e38f, lsum = 0.f;

        int nkb = qb + 1;
        // prologue: stage tile 0
#pragma unroll
        for (int si = 0; si < 4; ++si) {
            int row = srow + si * 16;
            gload_lds16(Kp + (size_t)row * HDIM + sp * 8, &Ks[buf][row * 64 + kseg * 8]);
            gload_lds16(VTp + (size_t)row * SEQ + sp * 8, &Vt[buf][row * 64 + kseg * 8]);
        }
        for (int kvb = 0; kvb < nkb; ++kvb) {
            int tb = kvb << 6;
            __syncthreads();   // drains stage of current buf
            if (kvb + 1 < nkb) {
                int tb2 = tb + 64, bn = buf ^ 1;
#pragma unroll
                for (int si = 0; si < 4; ++si) {
                    int row = srow + si * 16;
                    gload_lds16(Kp + (size_t)(tb2 + row) * HDIM + sp * 8, &Ks[bn][row * 64 + kseg * 8]);
                    gload_lds16(VTp + (size_t)row * SEQ + tb2 + sp * 8, &Vt[bn][row * 64 + kseg * 8]);
                }
            }
            int dq = qrow0 - tb;     // wave-uniform; >=0 when active
            if (dq >= 0) {
                bool has1 = dq >= 32;
                const short* ksb = &Ks[buf][0];
                const short* vtb = &Vt[buf][0];
                // ---- S^T = K . Q^T  (two 32x32 tiles over kv)
                f32x16 s0 = {}, s1 = {};
                __builtin_amdgcn_s_setprio(1);
#pragma unroll
                for (int ks = 0; ks < 4; ++ks) {
                    bf16x8 kf = *(const bf16x8*)&ksb[l31 * 64 + ((ks * 16 + hi * 8) ^ swl)];
                    s0 = __builtin_amdgcn_mfma_f32_32x32x16_bf16(kf, qf[ks], s0, 0, 0, 0);
                }
                if (has1) {
#pragma unroll
                    for (int ks = 0; ks < 4; ++ks) {
                        bf16x8 kf = *(const bf16x8*)&ksb[(32 + l31) * 64 + ((ks * 16 + hi * 8) ^ swl)];
                        s1 = __builtin_amdgcn_mfma_f32_32x32x16_bf16(kf, qf[ks], s1, 0, 0, 0);
                    }
                }
                __builtin_amdgcn_s_setprio(0);
                // ---- diagonal mask (only the tile containing q==kv)
                if (dq == 0) {
                    int thr = l31 - 4 * hi;
#pragma unroll
                    for (int r = 0; r < 16; ++r) {
                        int crow = (r & 3) + 8 * (r >> 2);
                        s0[r] = (crow > thr) ? -3e38f : s0[r];
                    }
                } else if (dq == 32) {
                    int thr = l31 - 4 * hi;
#pragma unroll
                    for (int r = 0; r < 16; ++r) {
                        int crow = (r & 3) + 8 * (r >> 2);
                        s1[r] = (crow > thr) ? -3e38f : s1[r];
                    }
                }
                // ---- in-lane max + cross-half
                float mv = s0[0];
#pragma unroll
                for (int r = 1; r < 16; ++r) mv = fmaxf(mv, s0[r]);
                if (has1) {
#pragma unroll
                    for (int r = 0; r < 16; ++r) mv = fmaxf(mv, s1[r]);
                }
                mv = fmaxf(mv, __shfl_xor(mv, 32));
                // ---- defer-max rescale (T13)
                if (!__all(mv - m <= 10.0f)) {
                    float mn = fmaxf(m, mv);
                    float a = exp2f(m - mn);
                    m = mn;
                    lsum *= a;
#pragma unroll
                    for (int r = 0; r < 16; ++r) { o0[r] *= a; o1[r] *= a; }
                }
                // ---- P = exp2(S - m), in-lane sum + cross-half
                float ps = 0.f;
#pragma unroll
                for (int r = 0; r < 16; ++r) { float e = exp2f(s0[r] - m); s0[r] = e; ps += e; }
                if (has1) {
#pragma unroll
                    for (int r = 0; r < 16; ++r) { float e = exp2f(s1[r] - m); s1[r] = e; ps += e; }
                }
                ps += __shfl_xor(ps, 32);
                lsum += ps;
                // ---- pack P to bf16x2 words: W[u] covers kv pair (8*(u>>1)+4*hi+2*(u&1) .. +1)
                uint32_t W0[8], W1[8];
#pragma unroll
                for (int u = 0; u < 8; ++u) W0[u] = cvtpk_bf16(s0[2 * u], s0[2 * u + 1]);
                if (has1) {
#pragma unroll
                    for (int u = 0; u < 8; ++u) W1[u] = cvtpk_bf16(s1[2 * u], s1[2 * u + 1]);
                }
                // ---- cross-half exchange (one shfl moves both directions)
                uint32_t g0[4], g1[4];
#pragma unroll
                for (int ab = 0; ab < 4; ++ab) {
                    int ap = ab >> 1, bb = ab & 1;
                    uint32_t swv = hi ? W0[4 * ap + bb] : W0[4 * ap + 2 + bb];
                    g0[ab] = __shfl_xor(swv, 32);
                }
                if (has1) {
#pragma unroll
                    for (int ab = 0; ab < 4; ++ab) {
                        int ap = ab >> 1, bb = ab & 1;
                        uint32_t swv = hi ? W1[4 * ap + bb] : W1[4 * ap + 2 + bb];
                        g1[ab] = __shfl_xor(swv, 32);
                    }
                }
                // ---- O^T += V^T . P^T
                __builtin_amdgcn_s_setprio(1);
#pragma unroll
                for (int dt = 0; dt < 2; ++dt) {
#pragma unroll
                    for (int ks = 0; ks < 4; ++ks) {
                        if (ks < 2 || has1) {
                            const uint32_t* W = (ks < 2) ? W0 : W1;
                            const uint32_t* g = (ks < 2) ? g0 : g1;
                            int ap = ks & 1;
                            union { uint32_t u[4]; bf16x8 v; } pa;
                            pa.u[0] = hi ? g[ap * 2 + 0] : W[4 * ap + 0];
                            pa.u[1] = hi ? g[ap * 2 + 1] : W[4 * ap + 1];
                            pa.u[2] = hi ? W[4 * ap + 2] : g[ap * 2 + 0];
                            pa.u[3] = hi ? W[4 * ap + 3] : g[ap * 2 + 1];
                            bf16x8 vf = *(const bf16x8*)&vtb[(dt * 32 + l31) * 64 + ((ks * 16 + hi * 8) ^ swl)];
                            if (dt == 0)
                                o0 = __builtin_amdgcn_mfma_f32_32x32x16_bf16(vf, pa.v, o0, 0, 0, 0);
                            else
                                o1 = __builtin_amdgcn_mfma_f32_32x32x16_bf16(vf, pa.v, o1, 0, 0, 0);
                        }
                    }
                }
                __builtin_amdgcn_s_setprio(0);
            }
            buf ^= 1;
        }
        // ---- epilogue: lane-local divide; O^T layout -> scatter 2B stores
        float inv = 1.0f / lsum;
        short* outp = &attn_out[((size_t)(b * SEQ) + myq) * D_MODEL + h * HDIM + 4 * hi];
#pragma unroll
        for (int r = 0; r < 16; ++r) {
            int d = (r & 3) + 8 * (r >> 2);
            outp[d] = f2bf(o0[r] * inv);
            outp[32 + d] = f2bf(o1[r] * inv);
        }
    }
}

// ---------------------------------------------------------------- launch
extern "C" void kernel_launch(void* const* d_in, const int* in_sizes, int n_in,
                              void* d_out, int out_size, void* d_ws, size_t ws_size,
                              hipStream_t stream) {
    const float* x  = (const float*)d_in[0];
    const float* wq = (const float*)d_in[1];
    const float* bq = (const float*)d_in[2];
    const float* wk = (const float*)d_in[3];
    const float* bk = (const float*)d_in[4];
    const float* wv = (const float*)d_in[5];
    const float* bv = (const float*)d_in[6];
    const float* wo = (const float*)d_in[7];
    const float* bo = (const float*)d_in[8];
    float* out = (float*)d_out;

    char* ws = (char*)d_ws;
    size_t off = 0;
    auto alloc = [&](size_t bytes) {
        void* p = ws + off;
        off += (bytes + 255) & ~(size_t)255;
        return p;
    };
    short* xb   = (short*)alloc((size_t)M_ROWS * D_MODEL * 2);
    short* qkvT = (short*)alloc((size_t)3 * D_MODEL * D_MODEL * 2);
    short* woT  = (short*)alloc((size_t)D_MODEL * D_MODEL * 2);
    short* qkv  = (short*)alloc((size_t)3 * BHTD * 2);
    short* ao   = (short*)alloc((size_t)M_ROWS * D_MODEL * 2);
    short* vt_g = xb;   // xb dead after QKV GEMM; exact size match

    f32_to_bf16_k<<<dim3(M_ROWS * D_MODEL / (256 * 4)), dim3(256), 0, stream>>>(
        x, xb, M_ROWS * D_MODEL);
    transpose_pack_k<<<dim3(32, 32, 4), dim3(32, 8), 0, stream>>>(wq, wk, wv, wo, qkvT, woT);
    gemm128<0><<<dim3(M_ROWS / 128, 3 * D_MODEL / 128), dim3(256), 0, stream>>>(
        xb, qkvT, bq, bk, bv, qkv, nullptr, D_MODEL);
    vt_transpose_k<<<dim3(SEQ / 64, BATCH * NHEADS), dim3(256), 0, stream>>>(
        qkv + 2 * BHTD, vt_g);
    attn_kernel<<<dim3(8, 128), dim3(128), 0, stream>>>(
        qkv, qkv + BHTD, vt_g, ao);
    gemm128<1><<<dim3(M_ROWS / 128, D_MODEL / 128), dim3(256), 0, stream>>>(
        ao, woT, bo, nullptr, nullptr, nullptr, out, D_MODEL);
}